// Round 1
// baseline (55.322 us; speedup 1.0000x reference)
//
#include <hip/hip_runtime.h>

#define NB 4
#define NC 128
#define NH 128
#define NW 128
#define EPSV 0.2f

// ---------------- Kernel 1: channel mean -----------------------------------
// mean[b,h,w] = (1/NC) * sum_c x[b,c,h,w].  float4 over (h,w).
__global__ __launch_bounds__(256) void mean_kernel(const float* __restrict__ x,
                                                   float* __restrict__ mean) {
    int idx = blockIdx.x * 256 + threadIdx.x;       // over NB*NH*NW/4 = 16384
    int b = idx >> 12;                              // NH*NW/4 = 4096 per batch
    int pos4 = idx & 4095;
    const float4* xb = (const float4*)(x + (size_t)b * NC * NH * NW);
    float4 acc = make_float4(0.f, 0.f, 0.f, 0.f);
    #pragma unroll 4
    for (int c = 0; c < NC; ++c) {
        float4 v = xb[c * (NH * NW / 4) + pos4];
        acc.x += v.x; acc.y += v.y; acc.z += v.z; acc.w += v.w;
    }
    const float inv = 1.0f / NC;
    acc.x *= inv; acc.y *= inv; acc.z *= inv; acc.w *= inv;
    ((float4*)(mean + (size_t)b * NH * NW))[pos4] = acc;
}

// ---------------- Kernel 2: weights + CARAFE reassembly --------------------
// block: (bh = b*NH + h, cq = channel quarter).  256 threads.
// lanes 0..127 compute 9 softmax weights per w into LDS, then all 256
// threads sweep 32 channels (2 per iter), each writing a 2x2 output block.
__global__ __launch_bounds__(256) void carafe_kernel(const float* __restrict__ x,
                                                     const float* __restrict__ mean,
                                                     float* __restrict__ out) {
    const int bh = blockIdx.x;
    const int b  = bh / NH;
    const int h  = bh % NH;
    const int cq = blockIdx.y;          // 0..3

    __shared__ float wgt[9][NW];        // 4.5 KB

    const int tid = threadIdx.x;
    const float* mb = mean + (size_t)b * NH * NW;

    if (tid < NW) {
        const int w = tid;
        const float mc = mb[h * NW + w];
        float v[9];
        float vmax = -1e30f;
        #pragma unroll
        for (int ky = -1; ky <= 1; ++ky) {
            #pragma unroll
            for (int kx = -1; kx <= 1; ++kx) {
                const int hh = h + ky, ww = w + kx;
                const float mp = (hh >= 0 && hh < NH && ww >= 0 && ww < NW)
                                     ? mb[hh * NW + ww] : 0.0f;
                const float g = mp - mc;
                const float val = 1.0f / (g * g + EPSV);
                v[(ky + 1) * 3 + (kx + 1)] = val;
                vmax = fmaxf(vmax, val);
            }
        }
        float sum = 0.f;
        #pragma unroll
        for (int k = 0; k < 9; ++k) { v[k] = __expf(v[k] - vmax); sum += v[k]; }
        const float rs = 1.0f / sum;
        #pragma unroll
        for (int k = 0; k < 9; ++k) wgt[k][w] = v[k] * rs;
    }
    __syncthreads();

    const int w     = tid & (NW - 1);   // 0..127
    const int chalf = tid >> 7;         // 0 or 1

    float wk[9];
    #pragma unroll
    for (int k = 0; k < 9; ++k) wk[k] = wgt[k][w];

    // precompute row/col validity (uniform in h across block; w-edges diverge
    // only in 2 lanes per wave)
    const bool hm = (h - 1 >= 0), hp = (h + 1 < NH);
    const bool wm = (w - 1 >= 0), wp = (w + 1 < NW);

    for (int it = 0; it < (NC / 4) / 2; ++it) {       // 16 iters, 2 ch each
        const int c = cq * (NC / 4) + it * 2 + chalf;
        const float* xb = x + ((size_t)(b * NC + c)) * NH * NW;
        float val = 0.f;
        #pragma unroll
        for (int ky = -1; ky <= 1; ++ky) {
            const int hh = h + ky;
            if ((ky == -1 && !hm) || (ky == 1 && !hp)) continue;
            const float* row = xb + hh * NW;
            const float c0 = wm ? row[w - 1] : 0.0f;
            const float c1 = row[w];
            const float c2 = wp ? row[w + 1] : 0.0f;
            val += wk[(ky + 1) * 3 + 0] * c0;
            val += wk[(ky + 1) * 3 + 1] * c1;
            val += wk[(ky + 1) * 3 + 2] * c2;
        }
        const float2 v2 = make_float2(val, val);
        float* rowb = out + (((size_t)(b * NC + c)) * (NH * 2) + 2 * h) * (NW * 2) + 2 * w;
        *(float2*)(rowb)          = v2;   // row 2h
        *(float2*)(rowb + NW * 2) = v2;   // row 2h+1
    }
}

extern "C" void kernel_launch(void* const* d_in, const int* in_sizes, int n_in,
                              void* d_out, int out_size, void* d_ws, size_t ws_size,
                              hipStream_t stream) {
    const float* x = (const float*)d_in[0];
    float* out = (float*)d_out;
    float* mean = (float*)d_ws;   // NB*NH*NW*4 = 256 KB

    // kernel 1: 16384 threads
    mean_kernel<<<dim3((NB * NH * NW / 4) / 256), dim3(256), 0, stream>>>(x, mean);

    // kernel 2: (B*H, 4 channel quarters)
    carafe_kernel<<<dim3(NB * NH, 4), dim3(256), 0, stream>>>(x, mean, out);
}

// Round 3
// 39.567 us; speedup vs baseline: 1.3982x; 1.3982x over previous
//
#include <hip/hip_runtime.h>

#define NB 4
#define NC 128
#define NH 128
#define NW 128
#define EPSV 0.2f
#define TH 2

typedef float v2f __attribute__((ext_vector_type(2)));

// ---------------- Kernel 1: channel mean -----------------------------------
// 512 blocks x 256 thr. Block covers 32 float4 positions; threads are
// (pos 0..31) x (cgroup 0..7), each summing 16 channels; LDS reduce 8-way.
__global__ __launch_bounds__(256) void mean_kernel(const float* __restrict__ x,
                                                   float* __restrict__ mean) {
    const int tid = threadIdx.x;
    const int pos = tid & 31;        // 0..31
    const int cg  = tid >> 5;        // 0..7
    const int gpos = blockIdx.x * 32 + pos;   // 0..16383 over NB*NH*NW/4
    const int b    = gpos >> 12;              // 4096 float4 per batch
    const int pos4 = gpos & 4095;

    const float4* x4 = (const float4*)x;
    float4 acc = make_float4(0.f, 0.f, 0.f, 0.f);
    const int cbase = (b * NC + cg * 16) * (NH * NW / 4) + pos4;
    #pragma unroll
    for (int cc = 0; cc < 16; ++cc) {
        float4 v = x4[cbase + cc * (NH * NW / 4)];
        acc.x += v.x; acc.y += v.y; acc.z += v.z; acc.w += v.w;
    }

    __shared__ float4 red[256];
    red[tid] = acc;
    __syncthreads();
    if (tid < 32) {
        float4 s = red[tid];
        #pragma unroll
        for (int g = 1; g < 8; ++g) {
            float4 v = red[tid + 32 * g];
            s.x += v.x; s.y += v.y; s.z += v.z; s.w += v.w;
        }
        const float inv = 1.0f / NC;
        s.x *= inv; s.y *= inv; s.z *= inv; s.w *= inv;
        ((float4*)mean)[blockIdx.x * 32 + tid] = s;
    }
}

// ---------------- Kernel 2: weights + CARAFE reassembly --------------------
// block: (b, h-pair, cq). 256 threads. Phase 1: 256 softmaxes (2 rows x 128 w)
// into LDS. Phase 2: sweep 32 channels (2 at a time), each thread computes
// 2 source rows x 1 w -> writes 4 upsampled rows as nontemporal float2.
__global__ __launch_bounds__(256) void carafe_kernel(const float* __restrict__ x,
                                                     const float* __restrict__ mean,
                                                     float* __restrict__ out) {
    // XCD-aware swizzle: gridDim.x = 256 (divisible by 8); blocks with
    // consecutive logical index (same b, adjacent h-pairs) share an XCD.
    const int nx = gridDim.x;
    const int chunk = nx >> 3;
    const int bid = blockIdx.x;
    const int swz = (bid & 7) * chunk + (bid >> 3);

    const int b  = swz >> 6;          // 64 h-pairs per batch
    const int h0 = (swz & 63) * TH;
    const int cq = blockIdx.y;        // 0..3

    __shared__ float wgt[TH][9][NW];  // 9 KB

    const int tid = threadIdx.x;
    const float* mb = mean + (size_t)b * NH * NW;

    {   // phase 1: weights for rows h0, h0+1
        const int r = tid >> 7;       // 0..1
        const int w = tid & 127;
        const int h = h0 + r;
        const float mc = mb[h * NW + w];
        float v[9];
        float vmax = -1e30f;
        #pragma unroll
        for (int ky = -1; ky <= 1; ++ky) {
            #pragma unroll
            for (int kx = -1; kx <= 1; ++kx) {
                const int hh = h + ky, ww = w + kx;
                const float mp = (hh >= 0 && hh < NH && ww >= 0 && ww < NW)
                                     ? mb[hh * NW + ww] : 0.0f;
                const float g = mp - mc;
                const float val = 1.0f / (g * g + EPSV);
                v[(ky + 1) * 3 + (kx + 1)] = val;
                vmax = fmaxf(vmax, val);
            }
        }
        float sum = 0.f;
        #pragma unroll
        for (int k = 0; k < 9; ++k) { v[k] = __expf(v[k] - vmax); sum += v[k]; }
        const float rs = 1.0f / sum;
        #pragma unroll
        for (int k = 0; k < 9; ++k) wgt[r][k][w] = v[k] * rs;
    }
    __syncthreads();

    const int w     = tid & (NW - 1);
    const int chalf = tid >> 7;

    float wk0[9], wk1[9];
    #pragma unroll
    for (int k = 0; k < 9; ++k) { wk0[k] = wgt[0][k][w]; wk1[k] = wgt[1][k][w]; }

    const bool hm = (h0 > 0);             // row h0-1 valid
    const bool hp = (h0 + TH < NH);       // row h0+2 valid
    const bool wm = (w > 0), wp = (w < NW - 1);

    for (int it = 0; it < 16; ++it) {     // 32 channels, 2 per iter
        const int c = cq * 32 + it * 2 + chalf;
        const float* xb = x + ((size_t)(b * NC + c)) * (NH * NW);

        float a[4][3];                    // rows h0-1 .. h0+2, taps w-1..w+1
        #pragma unroll
        for (int rr = 0; rr < 4; ++rr) {
            const int hh = h0 - 1 + rr;
            const bool hv = (rr == 0) ? hm : ((rr == 3) ? hp : true);
            const float* row = xb + hh * NW;
            a[rr][0] = (hv && wm) ? row[w - 1] : 0.f;
            a[rr][1] = hv ? row[w] : 0.f;
            a[rr][2] = (hv && wp) ? row[w + 1] : 0.f;
        }

        float v0 = 0.f, v1 = 0.f;
        #pragma unroll
        for (int ky = 0; ky < 3; ++ky) {
            #pragma unroll
            for (int kx = 0; kx < 3; ++kx) {
                v0 += wk0[ky * 3 + kx] * a[ky][kx];
                v1 += wk1[ky * 3 + kx] * a[ky + 1][kx];
            }
        }

        float* outc = out + ((size_t)(b * NC + c)) * (NH * 2) * (NW * 2);
        float* r0 = outc + (size_t)(2 * h0) * (NW * 2) + 2 * w;
        const v2f p0 = {v0, v0};
        const v2f p1 = {v1, v1};
        __builtin_nontemporal_store(p0, (v2f*)(r0));
        __builtin_nontemporal_store(p0, (v2f*)(r0 + (NW * 2)));
        __builtin_nontemporal_store(p1, (v2f*)(r0 + 2 * (NW * 2)));
        __builtin_nontemporal_store(p1, (v2f*)(r0 + 3 * (NW * 2)));
    }
}

extern "C" void kernel_launch(void* const* d_in, const int* in_sizes, int n_in,
                              void* d_out, int out_size, void* d_ws, size_t ws_size,
                              hipStream_t stream) {
    const float* x = (const float*)d_in[0];
    float* out = (float*)d_out;
    float* mean = (float*)d_ws;   // NB*NH*NW*4 = 256 KB

    mean_kernel<<<dim3(512), dim3(256), 0, stream>>>(x, mean);
    carafe_kernel<<<dim3(NB * NH / TH, 4), dim3(256), 0, stream>>>(x, mean, out);
}

// Round 4
// 33.954 us; speedup vs baseline: 1.6293x; 1.1653x over previous
//
#include <hip/hip_runtime.h>

#define NB 4
#define NC 128
#define NH 128
#define NW 128
#define EPSV 0.2f
#define TH 2

typedef float v4f __attribute__((ext_vector_type(4)));

// One fused kernel. Grid: 256 blocks = (b, h-pair), XCD-swizzled. 512 threads.
// Phase A: channel-mean rows h0-1..h0+2 -> LDS (each thread sums 128 ch for
//          one (row,w) position; loads coalesced across w, independent -> MLP).
// Phase B: 9-tap softmax weights for rows h0,h0+1 -> LDS.
// Phase C: reassembly; thread = (w-pair, channel-group of 16); all output
//          stores are 16B nontemporal float4 (1KB per wave-store).
__global__ __launch_bounds__(512) void fused_carafe(const float* __restrict__ x,
                                                    float* __restrict__ out) {
    // XCD-aware swizzle (256 blocks, 8 XCDs, bijective): adjacent h-pairs of
    // the same batch land on the same XCD for halo L2 reuse.
    const int chunk = gridDim.x >> 3;            // 32
    const int bid = blockIdx.x;
    const int swz = (bid & 7) * chunk + (bid >> 3);
    const int b  = swz >> 6;
    const int h0 = (swz & 63) * TH;

    __shared__ float mrow[4][NW];                // mean rows h0-1..h0+2
    __shared__ float wgt[TH][9][NW];             // softmax weights

    const int tid = threadIdx.x;

    // ---------------- Phase A: channel means ----------------
    {
        const int r = tid >> 7;                  // 0..3
        const int w = tid & 127;
        const int hh = h0 - 1 + r;
        float s = 0.f;
        if (hh >= 0 && hh < NH) {
            const float* px = x + ((size_t)b * NC * NH + hh) * NW + w;
            #pragma unroll 16
            for (int c = 0; c < NC; ++c)
                s += px[(size_t)c * NH * NW];
        }
        mrow[r][w] = s * (1.0f / NC);            // out-of-range row -> 0 (zero pad)
    }
    __syncthreads();

    // ---------------- Phase B: softmax weights ----------------
    if (tid < 256) {
        const int r = tid >> 7;                  // 0..1 -> source row h0+r
        const int w = tid & 127;
        const float mc = mrow[r + 1][w];
        float v[9];
        float vmax = -1e30f;
        #pragma unroll
        for (int ky = 0; ky < 3; ++ky) {
            #pragma unroll
            for (int kx = -1; kx <= 1; ++kx) {
                const int ww = w + kx;
                const float mp = (ww >= 0 && ww < NW) ? mrow[r + ky][ww] : 0.f;
                const float g = mp - mc;
                const float val = 1.0f / (g * g + EPSV);
                v[ky * 3 + kx + 1] = val;
                vmax = fmaxf(vmax, val);
            }
        }
        float sum = 0.f;
        #pragma unroll
        for (int k = 0; k < 9; ++k) { v[k] = __expf(v[k] - vmax); sum += v[k]; }
        const float rs = 1.0f / sum;
        #pragma unroll
        for (int k = 0; k < 9; ++k) wgt[r][k][w] = v[k] * rs;
    }
    __syncthreads();

    // ---------------- Phase C: reassembly ----------------
    const int wp = tid & 63;                     // w-pair: source cols 2wp, 2wp+1
    const int cg = tid >> 6;                     // 0..7 -> 16 channels each
    const int wa = 2 * wp;

    // 4 weight sets: (source row 0/1) x (col a/b)
    float wA0[9], wB0[9], wA1[9], wB1[9];
    #pragma unroll
    for (int k = 0; k < 9; ++k) {
        wA0[k] = wgt[0][k][wa];  wB0[k] = wgt[0][k][wa + 1];
        wA1[k] = wgt[1][k][wa];  wB1[k] = wgt[1][k][wa + 1];
    }

    const bool rv0 = (h0 > 0), rv3 = (h0 + 2 < NH);
    const bool tv0 = (wp > 0), tv3 = (wp < 63);

    #pragma unroll 2
    for (int i = 0; i < 16; ++i) {
        const int c = cg * 16 + i;
        const float* xc = x + ((size_t)(b * NC + c)) * (NH * NW);

        float a[4][4];                           // rows h0-1..h0+2, taps wa-1..wa+2
        #pragma unroll
        for (int rr = 0; rr < 4; ++rr) {
            const int hh = h0 - 1 + rr;
            const bool rv = (rr == 0) ? rv0 : ((rr == 3) ? rv3 : true);
            const float* row = xc + hh * NW + wa;
            a[rr][0] = (rv && tv0) ? row[-1] : 0.f;
            a[rr][1] = rv ? row[0] : 0.f;
            a[rr][2] = rv ? row[1] : 0.f;
            a[rr][3] = (rv && tv3) ? row[2] : 0.f;
        }

        float v0a = 0.f, v0b = 0.f, v1a = 0.f, v1b = 0.f;
        #pragma unroll
        for (int ky = 0; ky < 3; ++ky) {
            #pragma unroll
            for (int kx = 0; kx < 3; ++kx) {
                const int k = ky * 3 + kx;
                v0a += wA0[k] * a[ky][kx];
                v0b += wB0[k] * a[ky][kx + 1];
                v1a += wA1[k] * a[ky + 1][kx];
                v1b += wB1[k] * a[ky + 1][kx + 1];
            }
        }

        float* o = out + ((size_t)(b * NC + c) * (NH * 2) + 2 * h0) * (NW * 2) + 4 * wp;
        const v4f p0 = {v0a, v0a, v0b, v0b};
        const v4f p1 = {v1a, v1a, v1b, v1b};
        __builtin_nontemporal_store(p0, (v4f*)(o));
        __builtin_nontemporal_store(p0, (v4f*)(o + (NW * 2)));
        __builtin_nontemporal_store(p1, (v4f*)(o + 2 * (NW * 2)));
        __builtin_nontemporal_store(p1, (v4f*)(o + 3 * (NW * 2)));
    }
}

extern "C" void kernel_launch(void* const* d_in, const int* in_sizes, int n_in,
                              void* d_out, int out_size, void* d_ws, size_t ws_size,
                              hipStream_t stream) {
    const float* x = (const float*)d_in[0];
    float* out = (float*)d_out;
    fused_carafe<<<dim3(NB * NH / TH), dim3(512), 0, stream>>>(x, out);
}